// Round 10
// baseline (232.816 us; speedup 1.0000x reference)
//
#include <hip/hip_runtime.h>

#define HW 4096  // 64*64 spatial

typedef float v2f __attribute__((ext_vector_type(2)));

// Static device scratch (24 MiB): qkv[m][b][o][h][w] fp32, m in {0:q,1:k,2:v}.
// Fully rewritten by qkv_proj before attn reads it on every launch -> graph-safe.
__device__ float g_qkv[3 * 8 * 64 * HW];

#if __has_builtin(__builtin_amdgcn_exp2f)
#define QSCALE 1.4426950408889634f            // prescale q by log2(e); exp2 = native v_exp_f32
__device__ __forceinline__ float fexp(float l) { return __builtin_amdgcn_exp2f(l); }
#else
#define QSCALE 1.0f
__device__ __forceinline__ float fexp(float l) { return __expf(l); }
#endif

// One block per (b,h). Register tile per thread: 2o x 8w x 3m = 48 accs held as
// 24 float2 -> the c-loop FMAs contract to v_pk_fma_f32 (packed fp32, full rate
// on CDNA4): VALU issue halves vs R9 (6144 -> 3072 cyc/wave). LDS instrs/thread
// drop 832 -> 512 (8x b128 x-reads + 24 scalar w-reads per c-quad). W rows
// stride 65 dwords: w-read banks = 2*(t>>3) mod 32, distinct per lane group ->
// conflict-free; x float4 reads 2-way = free.
__global__ __launch_bounds__(256, 2) void qkv_proj(
    const float* __restrict__ x,
    const float* __restrict__ wq,
    const float* __restrict__ wk,
    const float* __restrict__ wv)
{
    __shared__ float xs[64][64];      // [c][w] 16 KB
    __shared__ float wl[3][64][65];   // [m][o][c], stride 65
    const int t = threadIdx.x;
    const int b = blockIdx.x >> 6;
    const int h = blockIdx.x & 63;

    {
        const float* __restrict__ mats[3] = { wq, wk, wv };
        #pragma unroll
        for (int m = 0; m < 3; ++m)
            for (int i = t; i < 4096; i += 256) {
                int o = i >> 6, c = i & 63;
                wl[m][o][c] = mats[m][i];
            }
        const float* xrow = x + (size_t)b * 64 * HW + (size_t)h * 64;
        for (int i = t; i < 4096; i += 256) {
            int c = i >> 6, w = i & 63;
            xs[c][w] = xrow[(size_t)c * HW + w];
        }
    }
    __syncthreads();

    const int w0 = (t & 7) * 8;                    // 8-wide w tile
    const int o0 = (t >> 3) * 2;                   // 2-wide o tile

    v2f acc[3][2][4];                              // [m][oi][wp]
    #pragma unroll
    for (int m = 0; m < 3; ++m)
        #pragma unroll
        for (int oi = 0; oi < 2; ++oi)
            #pragma unroll
            for (int wp = 0; wp < 4; ++wp) acc[m][oi][wp] = (v2f){0.f, 0.f};

    #pragma unroll 4
    for (int cq = 0; cq < 16; ++cq) {
        const int c0 = cq * 4;
        v2f xa[4][4];                              // [ci][wp]
        #pragma unroll
        for (int ci = 0; ci < 4; ++ci) {
            float4 a = *(const float4*)&xs[c0 + ci][w0];       // aligned b128
            float4 c = *(const float4*)&xs[c0 + ci][w0 + 4];   // aligned b128
            xa[ci][0] = (v2f){a.x, a.y}; xa[ci][1] = (v2f){a.z, a.w};
            xa[ci][2] = (v2f){c.x, c.y}; xa[ci][3] = (v2f){c.z, c.w};
        }
        #pragma unroll
        for (int m = 0; m < 3; ++m)
            #pragma unroll
            for (int oi = 0; oi < 2; ++oi)
                #pragma unroll
                for (int ci = 0; ci < 4; ++ci) {
                    const float wv1 = wl[m][o0 + oi][c0 + ci];  // scalar b32, conflict-free
                    const v2f ws = (v2f){wv1, wv1};
                    #pragma unroll
                    for (int wp = 0; wp < 4; ++wp)
                        acc[m][oi][wp] += ws * xa[ci][wp];      // -> v_pk_fma_f32
                }
    }

    #pragma unroll
    for (int m = 0; m < 3; ++m) {
        float* op = g_qkv + ((size_t)m * 8 + b) * (64 * HW) + (size_t)h * 64 + w0;
        #pragma unroll
        for (int oi = 0; oi < 2; ++oi) {
            float4 v0 = { acc[m][oi][0].x, acc[m][oi][0].y, acc[m][oi][1].x, acc[m][oi][1].y };
            float4 v1 = { acc[m][oi][2].x, acc[m][oi][2].y, acc[m][oi][3].x, acc[m][oi][3].y };
            *(float4*)&op[(size_t)(o0 + oi) * HW]     = v0;    // coalesced 16B stores
            *(float4*)&op[(size_t)(o0 + oi) * HW + 4] = v1;
        }
    }
}

// One block per (b,o): 7x7 local attention, full 70x70 k/v halo in LDS.
// Thread owns a 4x4 pixel tile (R9 structure). New: pixel-PAIRS along w packed
// into float2 -> logit mul / den add / num fma become v_pk_* (exp stays scalar
// v_exp_f32, unpackable). Edge taps (4 of 28 per i) handled scalar via
// compile-time predicates. 3 blocks/CU (117.6 KB LDS).
// rel_w/rel_h dead (constant along 49-entry softmax axis -> shift-invariance).
// Zero padding + 1x1 conv => k=v=0 outside; logit q*0=0 still participates.
__global__ __launch_bounds__(256, 3) void attn(float* __restrict__ out)
{
    __shared__ float kv[70][140];     // k at [r][0..69], v at [r][70..139]
    const int t = threadIdx.x;
    const int b = blockIdx.x >> 6;
    const int o = blockIdx.x & 63;

    const float* qb = g_qkv + ((size_t)(0 * 8 + b) * 64 + o) * HW;
    const float* kb = g_qkv + ((size_t)(1 * 8 + b) * 64 + o) * HW;
    const float* vb = g_qkv + ((size_t)(2 * 8 + b) * 64 + o) * HW;

    for (int i = t; i < 70 * 70; i += 256) {
        int r = i / 70, c = i - r * 70;
        int gh = r - 3, gw = c - 3;
        float kk = 0.f, vv = 0.f;
        if ((unsigned)gh < 64u && (unsigned)gw < 64u) {
            kk = kb[gh * 64 + gw];
            vv = vb[gh * 64 + gw];
        }
        kv[r][c] = kk;
        kv[r][70 + c] = vv;
    }
    __syncthreads();

    const int r0 = (t >> 4) * 4;      // pixel-tile row base
    const int c0 = (t & 15) * 4;      // pixel-tile col base

    v2f qv2[4][2], den2[4][2], num2[4][2];
    #pragma unroll
    for (int i = 0; i < 4; ++i) {
        float4 q4 = *(const float4*)&qb[(r0 + i) * 64 + c0];
        qv2[i][0] = (v2f){q4.x * QSCALE, q4.y * QSCALE};
        qv2[i][1] = (v2f){q4.z * QSCALE, q4.w * QSCALE};
        den2[i][0] = (v2f){0.f, 0.f}; den2[i][1] = (v2f){0.f, 0.f};
        num2[i][0] = (v2f){0.f, 0.f}; num2[i][1] = (v2f){0.f, 0.f};
    }

    // halo rows r0..r0+9, cols c0..c0+9; pixel (i,j) active iff rr-i, cc-j in [0,7)
    #pragma unroll
    for (int rr = 0; rr < 10; ++rr) {
        #pragma unroll
        for (int cc = 0; cc < 10; ++cc) {
            const float kk = kv[r0 + rr][c0 + cc];        // pair -> ds_read2_b32
            const float vv = kv[r0 + rr][70 + c0 + cc];
            const v2f ks = (v2f){kk, kk};
            const v2f vs = (v2f){vv, vv};
            #pragma unroll
            for (int i = 0; i < 4; ++i) {
                if (rr - i >= 0 && rr - i < 7) {          // compile-time predicate
                    #pragma unroll
                    for (int jp = 0; jp < 2; ++jp) {
                        const int j0 = 2 * jp, j1 = 2 * jp + 1;
                        const bool a0 = (cc - j0 >= 0) && (cc - j0 < 7);   // compile-time
                        const bool a1 = (cc - j1 >= 0) && (cc - j1 < 7);
                        if (a0 && a1) {
                            v2f l = qv2[i][jp] * ks;                      // v_pk_mul_f32
                            v2f e = (v2f){fexp(l.x), fexp(l.y)};          // 2x v_exp_f32
                            den2[i][jp] += e;                             // v_pk_add_f32
                            num2[i][jp] += e * vs;                        // v_pk_fma_f32
                        } else if (a0) {
                            float e = fexp(qv2[i][jp].x * kk);
                            den2[i][jp].x += e;
                            num2[i][jp].x = fmaf(e, vv, num2[i][jp].x);
                        } else if (a1) {
                            float e = fexp(qv2[i][jp].y * kk);
                            den2[i][jp].y += e;
                            num2[i][jp].y = fmaf(e, vv, num2[i][jp].y);
                        }
                    }
                }
            }
        }
    }

    float* ob = out + ((size_t)(b * 64 + o)) * HW;
    #pragma unroll
    for (int i = 0; i < 4; ++i) {
        float4 v = { num2[i][0].x / den2[i][0].x, num2[i][0].y / den2[i][0].y,
                     num2[i][1].x / den2[i][1].x, num2[i][1].y / den2[i][1].y };
        *(float4*)&ob[(r0 + i) * 64 + c0] = v;
    }
}

extern "C" void kernel_launch(void* const* d_in, const int* in_sizes, int n_in,
                              void* d_out, int out_size, void* d_ws, size_t ws_size,
                              hipStream_t stream)
{
    // d_in: 0=x, 1=wq, 2=wk, 3=wv (fp32), 4=rel_w, 5=rel_h (dead: softmax
    // shift-invariance), 6=kernel_size(7), 7=padding(3) hardcoded.
    qkv_proj<<<dim3(512), dim3(256), 0, stream>>>(
        (const float*)d_in[0], (const float*)d_in[1],
        (const float*)d_in[2], (const float*)d_in[3]);
    attn<<<dim3(512), dim3(256), 0, stream>>>((float*)d_out);
}

// Round 11
// 117.609 us; speedup vs baseline: 1.9796x; 1.9796x over previous
//
#include <hip/hip_runtime.h>

#define HW 4096  // 64*64 spatial

// Static device scratch (24 MiB): qkv[m][b][o][h][w] fp32, m in {0:q,1:k,2:v}.
// Fully rewritten by qkv_proj before attn reads it on every launch -> graph-safe.
__device__ float g_qkv[3 * 8 * 64 * HW];

#if __has_builtin(__builtin_amdgcn_exp2f)
#define QSCALE 1.4426950408889634f            // prescale q by log2(e); exp2 is native v_exp_f32
__device__ __forceinline__ float fexp(float l) { return __builtin_amdgcn_exp2f(l); }
#else
#define QSCALE 1.0f
__device__ __forceinline__ float fexp(float l) { return __expf(l); }
#endif

// R9 configuration — the measured optimum (dur_us 115.9). R10's packed-float2
// variant spilled to scratch (FETCH 232 MB, WRITE 179 MB, VALUBusy 9%): ext
// vector arrays with per-element writes in divergent arms become addressable ->
// scratch allocation. Scalar accumulators + compile-time indices stay in VGPRs.
//
// One block per (b,h). Register-tiled: thread = (to,tw) computes 4o x 4w for all
// 3 matrices (48 independent accumulators -> no dep-chain stall). x via aligned
// float4 LDS reads (2-way alias = free). W rows stride 65 dwords + SCALAR reads:
// o-group bank step = 4*65 mod 32 = 4 -> 2-way = free.
__global__ __launch_bounds__(256, 2) void qkv_proj(
    const float* __restrict__ x,
    const float* __restrict__ wq,
    const float* __restrict__ wk,
    const float* __restrict__ wv)
{
    __shared__ float xs[64][64];      // [c][w] 16 KB
    __shared__ float wl[3][64][65];   // [m][o][c], stride 65
    const int t = threadIdx.x;
    const int b = blockIdx.x >> 6;
    const int h = blockIdx.x & 63;

    {
        const float* __restrict__ mats[3] = { wq, wk, wv };
        #pragma unroll
        for (int m = 0; m < 3; ++m)
            for (int i = t; i < 4096; i += 256) {
                int o = i >> 6, c = i & 63;
                wl[m][o][c] = mats[m][i];          // straight copy, consecutive-c writes
            }
        const float* xrow = x + (size_t)b * 64 * HW + (size_t)h * 64;
        for (int i = t; i < 4096; i += 256) {
            int c = i >> 6, w = i & 63;
            xs[c][w] = xrow[(size_t)c * HW + w];
        }
    }
    __syncthreads();

    const int w0 = (t & 15) * 4;                   // w-quad
    const int o0 = (t >> 4) * 4;                   // o-quad
    float acc[3][16];
    #pragma unroll
    for (int m = 0; m < 3; ++m)
        #pragma unroll
        for (int i = 0; i < 16; ++i) acc[m][i] = 0.f;

    #pragma unroll 4
    for (int cq = 0; cq < 16; ++cq) {
        const int c0 = cq * 4;
        float xa[4][4];                            // [ci][wi]
        #pragma unroll
        for (int ci = 0; ci < 4; ++ci)
            *(float4*)&xa[ci][0] = *(const float4*)&xs[c0 + ci][w0];   // aligned b128
        #pragma unroll
        for (int m = 0; m < 3; ++m)
            #pragma unroll
            for (int oi = 0; oi < 4; ++oi) {
                #pragma unroll
                for (int ci = 0; ci < 4; ++ci) {
                    const float wv1 = wl[m][o0 + oi][c0 + ci];  // scalar b32, 2-way = free
                    #pragma unroll
                    for (int wi = 0; wi < 4; ++wi)
                        acc[m][oi * 4 + wi] = fmaf(wv1, xa[ci][wi], acc[m][oi * 4 + wi]);
                }
            }
    }

    #pragma unroll
    for (int m = 0; m < 3; ++m) {
        float* op = g_qkv + ((size_t)m * 8 + b) * (64 * HW) + (size_t)h * 64 + w0;
        #pragma unroll
        for (int oi = 0; oi < 4; ++oi) {
            float4 v = { acc[m][oi * 4 + 0], acc[m][oi * 4 + 1],
                         acc[m][oi * 4 + 2], acc[m][oi * 4 + 3] };
            *(float4*)&op[(size_t)(o0 + oi) * HW] = v;         // 256B coalesced segments
        }
    }
}

// One block per (b,o): 7x7 local attention, full 70x70 k/v halo in LDS.
// Thread owns a 4x4 pixel tile: window union = 10x10 taps, 200 LDS dwords per
// 16 pixels. exp count/thread (784) is the VALU floor; scalar accumulators in
// flat arrays with compile-time indices -> pure VGPR allocation (no scratch).
// rel_w/rel_h dead (constant along 49-entry softmax axis -> shift-invariance).
// Zero padding + 1x1 conv => k=v=0 outside; logit q*0=0 still participates.
// k at kv[r][0..69], v at kv[r][70..139]: pair -> ds_read2_b32 offsets 0/70.
__global__ __launch_bounds__(256, 2) void attn(float* __restrict__ out)
{
    __shared__ float kv[70][140];     // 39.2 KB
    const int t = threadIdx.x;
    const int b = blockIdx.x >> 6;
    const int o = blockIdx.x & 63;

    const float* qb = g_qkv + ((size_t)(0 * 8 + b) * 64 + o) * HW;
    const float* kb = g_qkv + ((size_t)(1 * 8 + b) * 64 + o) * HW;
    const float* vb = g_qkv + ((size_t)(2 * 8 + b) * 64 + o) * HW;

    for (int i = t; i < 70 * 70; i += 256) {
        int r = i / 70, c = i - r * 70;
        int gh = r - 3, gw = c - 3;
        float kk = 0.f, vv = 0.f;
        if ((unsigned)gh < 64u && (unsigned)gw < 64u) {
            kk = kb[gh * 64 + gw];
            vv = vb[gh * 64 + gw];
        }
        kv[r][c] = kk;
        kv[r][70 + c] = vv;
    }
    __syncthreads();

    const int r0 = (t >> 4) * 4;      // pixel-tile row base (0..60)
    const int c0 = (t & 15) * 4;      // pixel-tile col base (0..60)

    float qv[16], den[16], num[16];
    #pragma unroll
    for (int i = 0; i < 4; ++i) {
        float4 q4 = *(const float4*)&qb[(r0 + i) * 64 + c0];
        qv[i * 4 + 0] = q4.x * QSCALE; qv[i * 4 + 1] = q4.y * QSCALE;
        qv[i * 4 + 2] = q4.z * QSCALE; qv[i * 4 + 3] = q4.w * QSCALE;
    }
    #pragma unroll
    for (int i = 0; i < 16; ++i) { den[i] = 0.f; num[i] = 0.f; }

    // halo rows r0..r0+9, cols c0..c0+9; pixel (i,j) active iff rr-i,cc-j in [0,7)
    #pragma unroll
    for (int rr = 0; rr < 10; ++rr) {
        #pragma unroll
        for (int cc = 0; cc < 10; ++cc) {
            const float kk = kv[r0 + rr][c0 + cc];        // pair -> ds_read2_b32
            const float vv = kv[r0 + rr][70 + c0 + cc];
            #pragma unroll
            for (int i = 0; i < 4; ++i) {
                if (rr - i >= 0 && rr - i < 7) {          // compile-time predicates
                    #pragma unroll
                    for (int j = 0; j < 4; ++j) {
                        if (cc - j >= 0 && cc - j < 7) {
                            float e = fexp(qv[i * 4 + j] * kk);
                            den[i * 4 + j] += e;
                            num[i * 4 + j] = fmaf(e, vv, num[i * 4 + j]);
                        }
                    }
                }
            }
        }
    }

    float* ob = out + ((size_t)(b * 64 + o)) * HW;
    #pragma unroll
    for (int i = 0; i < 4; ++i) {
        float4 v = { num[i * 4 + 0] / den[i * 4 + 0], num[i * 4 + 1] / den[i * 4 + 1],
                     num[i * 4 + 2] / den[i * 4 + 2], num[i * 4 + 3] / den[i * 4 + 3] };
        *(float4*)&ob[(r0 + i) * 64 + c0] = v;
    }
}

extern "C" void kernel_launch(void* const* d_in, const int* in_sizes, int n_in,
                              void* d_out, int out_size, void* d_ws, size_t ws_size,
                              hipStream_t stream)
{
    // d_in: 0=x, 1=wq, 2=wk, 3=wv (fp32), 4=rel_w, 5=rel_h (dead: softmax
    // shift-invariance), 6=kernel_size(7), 7=padding(3) hardcoded.
    qkv_proj<<<dim3(512), dim3(256), 0, stream>>>(
        (const float*)d_in[0], (const float*)d_in[1],
        (const float*)d_in[2], (const float*)d_in[3]);
    attn<<<dim3(512), dim3(256), 0, stream>>>((float*)d_out);
}